// Round 2
// baseline (279.667 us; speedup 1.0000x reference)
//
#include <hip/hip_runtime.h>

#define NUM_GRAPHS 512
#define NPG        1024
#define KSEL       512
#define NNODES     (NUM_GRAPHS * NPG)   // 524288
#define CFEAT      64
#define NEDGE      (16 * NNODES)        // 8388608
#define NWORDS     (NUM_GRAPHS * 32)    // 16384 table entries (u64 each)

typedef int   int4v   __attribute__((ext_vector_type(4)));
typedef float float4v __attribute__((ext_vector_type(4)));

__device__ __forceinline__ unsigned rotl32(unsigned v, int d) {
  return (v << d) | (v >> (32 - d));
}

// JAX threefry2x32: 20 rounds, 5 key injections.
__device__ __forceinline__ void tf2x32(unsigned k0, unsigned k1,
                                       unsigned x0, unsigned x1,
                                       unsigned& o0, unsigned& o1) {
  unsigned ks2 = k0 ^ k1 ^ 0x1BD11BDAu;
  x0 += k0; x1 += k1;
  x0 += x1; x1 = rotl32(x1, 13); x1 ^= x0;
  x0 += x1; x1 = rotl32(x1, 15); x1 ^= x0;
  x0 += x1; x1 = rotl32(x1, 26); x1 ^= x0;
  x0 += x1; x1 = rotl32(x1, 6);  x1 ^= x0;
  x0 += k1; x1 += ks2 + 1u;
  x0 += x1; x1 = rotl32(x1, 17); x1 ^= x0;
  x0 += x1; x1 = rotl32(x1, 29); x1 ^= x0;
  x0 += x1; x1 = rotl32(x1, 16); x1 ^= x0;
  x0 += x1; x1 = rotl32(x1, 24); x1 ^= x0;
  x0 += ks2; x1 += k0 + 2u;
  x0 += x1; x1 = rotl32(x1, 13); x1 ^= x0;
  x0 += x1; x1 = rotl32(x1, 15); x1 ^= x0;
  x0 += x1; x1 = rotl32(x1, 26); x1 ^= x0;
  x0 += x1; x1 = rotl32(x1, 6);  x1 ^= x0;
  x0 += k0; x1 += k1 + 3u;
  x0 += x1; x1 = rotl32(x1, 17); x1 ^= x0;
  x0 += x1; x1 = rotl32(x1, 29); x1 ^= x0;
  x0 += x1; x1 = rotl32(x1, 16); x1 ^= x0;
  x0 += x1; x1 = rotl32(x1, 24); x1 ^= x0;
  x0 += k1; x1 += ks2 + 4u;
  x0 += x1; x1 = rotl32(x1, 13); x1 ^= x0;
  x0 += x1; x1 = rotl32(x1, 15); x1 ^= x0;
  x0 += x1; x1 = rotl32(x1, 26); x1 ^= x0;
  x0 += x1; x1 = rotl32(x1, 6);  x1 ^= x0;
  x0 += ks2; x1 += k0 + 5u;
  o0 = x0; o1 = x1;
}

// One block (512 thr) per graph, pure compute.
// Selection = "512 smallest (key<<32|idx) u64s": O(N) histogram threshold
// (keys distinct -> flag[i] = (k_i <= T) exact), then BALLOT builds the
// 1024-bit membership bitmap directly; positions via wave-word popcount.
// No 1024-wide prefix scan, no sort. Writes tab, ids_ws, out_b, out_p.
__global__ __launch_bounds__(512) void tab_kernel(
    float* __restrict__ out_b, float* __restrict__ out_p,
    unsigned long long* __restrict__ tab,
    unsigned short* __restrict__ ids_ws) {
  __shared__ int bins[256];
  __shared__ unsigned long long cand[NPG];   // capacity-safe
  __shared__ unsigned long long words64[16]; // 1024-bit membership bitmap
  __shared__ int wbase[16];                  // exclusive popcount scan
  __shared__ int ccnt;
  __shared__ int sB, sR;
  __shared__ unsigned long long sT;

  const int g = blockIdx.x;
  const int tid = threadIdx.x;
  const int lane = tid & 63;
  const int wv = tid >> 6;

  unsigned kg0, kg1, sk0, sk1;
  tf2x32(0u, 42u, 0u, (unsigned)g, kg0, kg1);
  tf2x32(kg0, kg1, 0u, 1u, sk0, sk1);

  if (tid < 256) bins[tid] = 0;
  if (tid == 0) ccnt = 0;

  // keygen: 2 elements/thread in registers; wave w covers contiguous ids
  unsigned long long myk[2];
#pragma unroll
  for (int e = 0; e < 2; ++e) {
    int i = e * 512 + tid;
    unsigned b1, b2;
    tf2x32(sk0, sk1, 0u, (unsigned)i, b1, b2);
    unsigned key = b1 ^ b2;
    myk[e] = ((unsigned long long)key << 32) | (unsigned)i;
  }
  __syncthreads();

  // histogram on top 8 bits of key
#pragma unroll
  for (int e = 0; e < 2; ++e)
    atomicAdd(&bins[(int)(myk[e] >> 56)], 1);
  __syncthreads();

  // single-wave scan over 256 bins (4 bins/lane) + crossing-bin detect
  if (tid < 64) {
    int b0 = bins[4 * tid], b1 = bins[4 * tid + 1],
        b2 = bins[4 * tid + 2], b3 = bins[4 * tid + 3];
    int s = b0 + b1 + b2 + b3;
    int inc = s;
#pragma unroll
    for (int d = 1; d < 64; d <<= 1) {
      int t = __shfl_up(inc, d, 64);
      if (tid >= d) inc += t;
    }
    int excl = inc - s;
    int i0 = excl + b0, i1 = i0 + b1, i2 = i1 + b2, i3 = i2 + b3;
    if (excl < KSEL && KSEL <= i0) { sB = 4 * tid;     sR = KSEL - excl; }
    if (i0   < KSEL && KSEL <= i1) { sB = 4 * tid + 1; sR = KSEL - i0; }
    if (i1   < KSEL && KSEL <= i2) { sB = 4 * tid + 2; sR = KSEL - i1; }
    if (i2   < KSEL && KSEL <= i3) { sB = 4 * tid + 3; sR = KSEL - i2; }
  }
  __syncthreads();
  const int bstar = sB;
  const int r = sR;

  // collect candidates in the crossing bin
#pragma unroll
  for (int e = 0; e < 2; ++e) {
    if ((int)(myk[e] >> 56) == bstar) {
      int p = atomicAdd(&ccnt, 1);
      cand[p] = myk[e];
    }
  }
  __syncthreads();
  const int cnt = ccnt;
  // exact rank among candidates; T = r-th smallest in bin (rank r-1)
  if (tid < 64) {
    for (int c = tid; c < cnt; c += 64) {
      unsigned long long mine = cand[c];
      int rank = 0;
      for (int j = 0; j < cnt; ++j) rank += (cand[j] < mine) ? 1 : 0;
      if (rank == r - 1) sT = mine;
    }
  }
  __syncthreads();
  const unsigned long long T = sT;

  // membership bitmap via ballot: word (e*8+wv) covers ids [e*512+64*wv, +64)
  const bool sel0 = (myk[0] <= T);
  const bool sel1 = (myk[1] <= T);
  {
    unsigned long long b0 = __ballot(sel0);
    unsigned long long b1 = __ballot(sel1);
    if (lane == 0) {
      words64[wv] = b0;
      words64[8 + wv] = b1;
    }
  }
  __syncthreads();

  // exclusive scan of word popcounts (16 values, one wave)
  if (tid < 16) {
    int c = __popcll(words64[tid]);
    int inc = c;
#pragma unroll
    for (int d = 1; d < 16; d <<= 1) {
      int t = __shfl_up(inc, d, 64);
      if (tid >= d) inc += t;
    }
    wbase[tid] = inc - c;
  }
  __syncthreads();

  // scatter ids / batch / perm (positions from word base + lane popcount)
#pragma unroll
  for (int e = 0; e < 2; ++e) {
    bool sel = e ? sel1 : sel0;
    if (sel) {
      int i = e * 512 + tid;
      int wi = i >> 6;
      int l = i & 63;
      unsigned long long w = words64[wi];
      int pos = wbase[wi] + __popcll(w & ((1ull << l) - 1ull));
      ids_ws[g * KSEL + pos] = (unsigned short)i;
      out_b[g * KSEL + pos] = (float)g;
      out_p[g * KSEL + pos] = (float)(g * NPG + i);
    }
  }

  // packed lookup table: per 32 nodes, bitmap word + exclusive base
  if (tid < 32) {
    unsigned long long w64 = words64[tid >> 1];
    unsigned w32 = (unsigned)(w64 >> ((tid & 1) * 32));
    unsigned base = (unsigned)wbase[tid >> 1] +
                    ((tid & 1) ? (unsigned)__popc((unsigned)w64) : 0u);
    tab[g * 32 + tid] = (unsigned long long)w32 |
                        ((unsigned long long)base << 32);
  }
}

// Fused gather + edge filter. 256 blocks x 1024 thr, 1 block/CU.
// Full (bitmap,base) table in LDS: endpoint lookup = ds_read_b64 + popcount.
__global__ __launch_bounds__(1024) void fused_kernel(
    const float* __restrict__ x, const int* __restrict__ ei,
    const unsigned long long* __restrict__ tab,
    const unsigned short* __restrict__ ids_ws,
    float* __restrict__ out_x, float* __restrict__ out_e) {
  __shared__ unsigned long long ltab[NWORDS];   // 128 KB
  __shared__ unsigned short lids[1024];         // this block's gather rows

  const int tid = threadIdx.x;
  const int blk = blockIdx.x;

  // stage table (16 u64 per thread, coalesced)
#pragma unroll
  for (int k = 0; k < NWORDS / 1024; ++k) {
    ltab[k * 1024 + tid] = tab[k * 1024 + tid];
  }
  // this block's 1024 gather rows
  {
    const int row0 = blk * 1024;
    if (tid < 512) {
      ((unsigned*)lids)[tid] = ((const unsigned*)(ids_ws + row0))[tid];
    }
  }
  __syncthreads();

  // phase B: gather x rows. out rows [blk*1024, +1024), 16 float4/row
  {
    const float4v* xs = (const float4v*)x;
    float4v* xd = (float4v*)out_x;
    const int row0 = blk * 1024;
#pragma unroll
    for (int k = 0; k < 16; ++k) {
      int t = k * 1024 + tid;
      int r = t >> 4;           // local row 0..1023
      int c = t & 15;
      int row = row0 + r;       // global out row
      int g = row >> 9;         // graph
      int id = lids[r];
      float4v v = __builtin_nontemporal_load(
          &xs[((size_t)g * NPG + id) * 16 + c]);
      __builtin_nontemporal_store(v, &xd[(size_t)row * 16 + c]);
    }
  }

  // phase C: edges. 32 per thread, 4 chunks of 8.
#pragma unroll
  for (int k = 0; k < 4; ++k) {
    const int base = (((k * 256 + blk) * 1024) + tid) * 8;
    int4v s0 = __builtin_nontemporal_load((const int4v*)(ei + base));
    int4v s1 = __builtin_nontemporal_load((const int4v*)(ei + base + 4));
    int4v d0 = __builtin_nontemporal_load((const int4v*)(ei + (size_t)NEDGE + base));
    int4v d1 = __builtin_nontemporal_load((const int4v*)(ei + (size_t)NEDGE + base + 4));

    int src[8] = {s0.x, s0.y, s0.z, s0.w, s1.x, s1.y, s1.z, s1.w};
    int dst[8] = {d0.x, d0.y, d0.z, d0.w, d1.x, d1.y, d1.z, d1.w};

    int rrow[8], rcol[8];
#pragma unroll
    for (int j = 0; j < 8; ++j) {
      unsigned long long es = ltab[src[j] >> 5];
      unsigned long long ed = ltab[dst[j] >> 5];
      unsigned ws = (unsigned)es, wd = (unsigned)ed;
      int shs = src[j] & 31, shd = dst[j] & 31;
      bool sels = (ws >> shs) & 1u;
      bool seld = (wd >> shd) & 1u;
      int poss = (int)(es >> 32) + __popc(ws & ((1u << shs) - 1u));
      int posd = (int)(ed >> 32) + __popc(wd & ((1u << shd) - 1u));
      bool keep = sels && seld;
      rrow[j] = keep ? (((src[j] & ~1023) >> 1) + poss) : -1;
      rcol[j] = keep ? (((dst[j] & ~1023) >> 1) + posd) : -1;
    }

    float4v r0 = {(float)rrow[0], (float)rrow[1], (float)rrow[2], (float)rrow[3]};
    float4v r1 = {(float)rrow[4], (float)rrow[5], (float)rrow[6], (float)rrow[7]};
    float4v c0 = {(float)rcol[0], (float)rcol[1], (float)rcol[2], (float)rcol[3]};
    float4v c1 = {(float)rcol[4], (float)rcol[5], (float)rcol[6], (float)rcol[7]};
    __builtin_nontemporal_store(r0, (float4v*)(out_e + base));
    __builtin_nontemporal_store(r1, (float4v*)(out_e + base + 4));
    __builtin_nontemporal_store(c0, (float4v*)(out_e + (size_t)NEDGE + base));
    __builtin_nontemporal_store(c1, (float4v*)(out_e + (size_t)NEDGE + base + 4));
  }
}

extern "C" void kernel_launch(void* const* d_in, const int* in_sizes, int n_in,
                              void* d_out, int out_size, void* d_ws, size_t ws_size,
                              hipStream_t stream) {
  const float* x  = (const float*)d_in[0];
  const int*   ei = (const int*)d_in[1];

  float* out   = (float*)d_out;
  float* out_x = out;                                            // 16777216
  float* out_e = out + (size_t)NUM_GRAPHS * KSEL * CFEAT;        // 16777216
  float* out_b = out_e + 2 * (size_t)NEDGE;                      // 262144
  float* out_p = out_b + (size_t)NUM_GRAPHS * KSEL;              // 262144

  // d_ws layout: [0,128K) u64 table; [128K, 128K+512K) u16 ids
  unsigned long long* tab = (unsigned long long*)d_ws;
  unsigned short* ids_ws = (unsigned short*)((char*)d_ws + NWORDS * 8);

  tab_kernel<<<NUM_GRAPHS, 512, 0, stream>>>(out_b, out_p, tab, ids_ws);
  fused_kernel<<<256, 1024, 0, stream>>>(x, ei, tab, ids_ws, out_x, out_e);
}

// Round 3
// 276.506 us; speedup vs baseline: 1.0114x; 1.0114x over previous
//
#include <hip/hip_runtime.h>

#define NUM_GRAPHS 512
#define NPG        1024
#define KSEL       512
#define NNODES     (NUM_GRAPHS * NPG)   // 524288
#define CFEAT      64
#define NEDGE      (16 * NNODES)        // 8388608
#define NWORDS     (NUM_GRAPHS * 32)    // 16384 table entries (u64 each)

typedef int   int4v   __attribute__((ext_vector_type(4)));
typedef float float4v __attribute__((ext_vector_type(4)));

__device__ __forceinline__ unsigned rotl32(unsigned v, int d) {
  return (v << d) | (v >> (32 - d));
}

// JAX threefry2x32: 20 rounds, 5 key injections.
__device__ __forceinline__ void tf2x32(unsigned k0, unsigned k1,
                                       unsigned x0, unsigned x1,
                                       unsigned& o0, unsigned& o1) {
  unsigned ks2 = k0 ^ k1 ^ 0x1BD11BDAu;
  x0 += k0; x1 += k1;
  x0 += x1; x1 = rotl32(x1, 13); x1 ^= x0;
  x0 += x1; x1 = rotl32(x1, 15); x1 ^= x0;
  x0 += x1; x1 = rotl32(x1, 26); x1 ^= x0;
  x0 += x1; x1 = rotl32(x1, 6);  x1 ^= x0;
  x0 += k1; x1 += ks2 + 1u;
  x0 += x1; x1 = rotl32(x1, 17); x1 ^= x0;
  x0 += x1; x1 = rotl32(x1, 29); x1 ^= x0;
  x0 += x1; x1 = rotl32(x1, 16); x1 ^= x0;
  x0 += x1; x1 = rotl32(x1, 24); x1 ^= x0;
  x0 += ks2; x1 += k0 + 2u;
  x0 += x1; x1 = rotl32(x1, 13); x1 ^= x0;
  x0 += x1; x1 = rotl32(x1, 15); x1 ^= x0;
  x0 += x1; x1 = rotl32(x1, 26); x1 ^= x0;
  x0 += x1; x1 = rotl32(x1, 6);  x1 ^= x0;
  x0 += k0; x1 += k1 + 3u;
  x0 += x1; x1 = rotl32(x1, 17); x1 ^= x0;
  x0 += x1; x1 = rotl32(x1, 29); x1 ^= x0;
  x0 += x1; x1 = rotl32(x1, 16); x1 ^= x0;
  x0 += x1; x1 = rotl32(x1, 24); x1 ^= x0;
  x0 += k1; x1 += ks2 + 4u;
  x0 += x1; x1 = rotl32(x1, 13); x1 ^= x0;
  x0 += x1; x1 = rotl32(x1, 15); x1 ^= x0;
  x0 += x1; x1 = rotl32(x1, 26); x1 ^= x0;
  x0 += x1; x1 = rotl32(x1, 6);  x1 ^= x0;
  x0 += ks2; x1 += k0 + 5u;
  o0 = x0; o1 = x1;
}

// One block (512 thr) per graph.
// Selection = "512 smallest (key<<32|idx) u64s": O(N) histogram threshold
// (keys distinct -> sel[i] = (k_i <= T) exact), membership bitmap via
// __ballot, positions via word-popcount — only 5 barriers total.
// Then this block gathers its own graph's 512 x-rows (out rows
// [g*512, g*512+512)), so no ids workspace / second pass is needed.
__global__ __launch_bounds__(512) void select_kernel(
    const float* __restrict__ x, float* __restrict__ out_x,
    float* __restrict__ out_b, float* __restrict__ out_p,
    unsigned long long* __restrict__ tab) {
  __shared__ int bins[256];
  __shared__ unsigned long long cand[NPG];   // capacity-safe
  __shared__ unsigned long long words64[16]; // 1024-bit membership bitmap
  __shared__ int wbase[16];                  // exclusive popcount scan
  __shared__ short ids[KSEL];
  __shared__ int ccnt;
  __shared__ int sB, sR;
  __shared__ unsigned long long sT;

  const int g = blockIdx.x;
  const int tid = threadIdx.x;
  const int lane = tid & 63;
  const int wv = tid >> 6;

  unsigned kg0, kg1, sk0, sk1;
  tf2x32(0u, 42u, 0u, (unsigned)g, kg0, kg1);
  tf2x32(kg0, kg1, 0u, 1u, sk0, sk1);

  if (tid < 256) bins[tid] = 0;
  if (tid == 0) ccnt = 0;

  // keygen: 2 elements/thread in registers; wave wv covers contiguous ids
  unsigned long long myk[2];
#pragma unroll
  for (int e = 0; e < 2; ++e) {
    int i = e * 512 + tid;
    unsigned b1, b2;
    tf2x32(sk0, sk1, 0u, (unsigned)i, b1, b2);
    unsigned key = b1 ^ b2;
    myk[e] = ((unsigned long long)key << 32) | (unsigned)i;
  }
  __syncthreads();

  // histogram on top 8 bits of key
#pragma unroll
  for (int e = 0; e < 2; ++e)
    atomicAdd(&bins[(int)(myk[e] >> 56)], 1);
  __syncthreads();

  // single-wave scan over 256 bins (4 bins/lane) + crossing-bin detect
  if (tid < 64) {
    int b0 = bins[4 * tid], b1 = bins[4 * tid + 1],
        b2 = bins[4 * tid + 2], b3 = bins[4 * tid + 3];
    int s = b0 + b1 + b2 + b3;
    int inc = s;
#pragma unroll
    for (int d = 1; d < 64; d <<= 1) {
      int t = __shfl_up(inc, d, 64);
      if (tid >= d) inc += t;
    }
    int excl = inc - s;
    int i0 = excl + b0, i1 = i0 + b1, i2 = i1 + b2, i3 = i2 + b3;
    if (excl < KSEL && KSEL <= i0) { sB = 4 * tid;     sR = KSEL - excl; }
    if (i0   < KSEL && KSEL <= i1) { sB = 4 * tid + 1; sR = KSEL - i0; }
    if (i1   < KSEL && KSEL <= i2) { sB = 4 * tid + 2; sR = KSEL - i1; }
    if (i2   < KSEL && KSEL <= i3) { sB = 4 * tid + 3; sR = KSEL - i2; }
  }
  __syncthreads();
  const int bstar = sB;
  const int r = sR;

  // collect candidates in the crossing bin (expected count ~4)
#pragma unroll
  for (int e = 0; e < 2; ++e) {
    if ((int)(myk[e] >> 56) == bstar) {
      int p = atomicAdd(&ccnt, 1);
      cand[p] = myk[e];
    }
  }
  __syncthreads();
  const int cnt = ccnt;
  // exact rank among candidates; T = r-th smallest in bin (rank r-1)
  if (tid < 64) {
    for (int c = tid; c < cnt; c += 64) {
      unsigned long long mine = cand[c];
      int rank = 0;
      for (int j = 0; j < cnt; ++j) rank += (cand[j] < mine) ? 1 : 0;
      if (rank == r - 1) sT = mine;
    }
  }
  __syncthreads();
  const unsigned long long T = sT;

  // membership bitmap via ballot: word (e*8+wv) covers ids [e*512+64*wv,+64)
  const bool sel0 = (myk[0] <= T);
  const bool sel1 = (myk[1] <= T);
  {
    unsigned long long b0 = __ballot(sel0);
    unsigned long long b1 = __ballot(sel1);
    if (lane == 0) {
      words64[wv] = b0;
      words64[8 + wv] = b1;
    }
  }
  __syncthreads();

  // exclusive scan of word popcounts (16 values, one wave)
  if (tid < 16) {
    int c = __popcll(words64[tid]);
    int inc = c;
#pragma unroll
    for (int d = 1; d < 16; d <<= 1) {
      int t = __shfl_up(inc, d, 64);
      if (tid >= d) inc += t;
    }
    wbase[tid] = inc - c;
  }
  __syncthreads();

  // scatter ids / batch / perm (positions from word base + lane popcount)
#pragma unroll
  for (int e = 0; e < 2; ++e) {
    bool sel = e ? sel1 : sel0;
    if (sel) {
      int i = e * 512 + tid;
      int wi = i >> 6;
      int l = i & 63;
      unsigned long long w = words64[wi];
      int pos = wbase[wi] + __popcll(w & ((1ull << l) - 1ull));
      ids[pos] = (short)i;
      out_b[g * KSEL + pos] = (float)g;
      out_p[g * KSEL + pos] = (float)(g * NPG + i);
    }
  }

  // packed lookup table: per 32 nodes, bitmap word + exclusive base
  if (tid < 32) {
    unsigned long long w64 = words64[tid >> 1];
    unsigned w32 = (unsigned)(w64 >> ((tid & 1) * 32));
    unsigned base = (unsigned)wbase[tid >> 1] +
                    ((tid & 1) ? (unsigned)__popc((unsigned)w64) : 0u);
    tab[g * 32 + tid] = (unsigned long long)w32 |
                        ((unsigned long long)base << 32);
  }
  __syncthreads();

  // gather x rows for this graph: 512 rows x 16 float4, coalesced per row
  {
    const float4v* xs = (const float4v*)x + (size_t)g * (NPG * 16);
    float4v* xd = (float4v*)out_x + (size_t)g * (KSEL * 16);
#pragma unroll
    for (int k = 0; k < 16; ++k) {
      int t = k * 512 + tid;
      int rr = t >> 4;          // out row 0..511
      int c = t & 15;
      int id = (int)ids[rr];
      float4v v = __builtin_nontemporal_load(&xs[id * 16 + c]);
      __builtin_nontemporal_store(v, &xd[rr * 16 + c]);
    }
  }
}

// Edge filter only. 256 blocks x 1024 thr, full (bitmap,base) table in LDS:
// every endpoint lookup is one scattered ds_read_b64 + popcount.
__global__ __launch_bounds__(1024) void edge_kernel(
    const int* __restrict__ ei,
    const unsigned long long* __restrict__ tab,
    float* __restrict__ out_e) {
  __shared__ unsigned long long ltab[NWORDS];   // 128 KB

  const int tid = threadIdx.x;
  const int blk = blockIdx.x;

  // stage table (16 u64 per thread, coalesced)
#pragma unroll
  for (int k = 0; k < NWORDS / 1024; ++k) {
    ltab[k * 1024 + tid] = tab[k * 1024 + tid];
  }
  __syncthreads();

  // 32 edges per thread, 4 chunks of 8
#pragma unroll
  for (int k = 0; k < 4; ++k) {
    const int base = (((k * 256 + blk) * 1024) + tid) * 8;
    int4v s0 = __builtin_nontemporal_load((const int4v*)(ei + base));
    int4v s1 = __builtin_nontemporal_load((const int4v*)(ei + base + 4));
    int4v d0 = __builtin_nontemporal_load((const int4v*)(ei + (size_t)NEDGE + base));
    int4v d1 = __builtin_nontemporal_load((const int4v*)(ei + (size_t)NEDGE + base + 4));

    int src[8] = {s0.x, s0.y, s0.z, s0.w, s1.x, s1.y, s1.z, s1.w};
    int dst[8] = {d0.x, d0.y, d0.z, d0.w, d1.x, d1.y, d1.z, d1.w};

    int rrow[8], rcol[8];
#pragma unroll
    for (int j = 0; j < 8; ++j) {
      unsigned long long es = ltab[src[j] >> 5];
      unsigned long long ed = ltab[dst[j] >> 5];
      unsigned ws = (unsigned)es, wd = (unsigned)ed;
      int shs = src[j] & 31, shd = dst[j] & 31;
      bool sels = (ws >> shs) & 1u;
      bool seld = (wd >> shd) & 1u;
      int poss = (int)(es >> 32) + __popc(ws & ((1u << shs) - 1u));
      int posd = (int)(ed >> 32) + __popc(wd & ((1u << shd) - 1u));
      bool keep = sels && seld;
      rrow[j] = keep ? (((src[j] & ~1023) >> 1) + poss) : -1;
      rcol[j] = keep ? (((dst[j] & ~1023) >> 1) + posd) : -1;
    }

    float4v r0 = {(float)rrow[0], (float)rrow[1], (float)rrow[2], (float)rrow[3]};
    float4v r1 = {(float)rrow[4], (float)rrow[5], (float)rrow[6], (float)rrow[7]};
    float4v c0 = {(float)rcol[0], (float)rcol[1], (float)rcol[2], (float)rcol[3]};
    float4v c1 = {(float)rcol[4], (float)rcol[5], (float)rcol[6], (float)rcol[7]};
    __builtin_nontemporal_store(r0, (float4v*)(out_e + base));
    __builtin_nontemporal_store(r1, (float4v*)(out_e + base + 4));
    __builtin_nontemporal_store(c0, (float4v*)(out_e + (size_t)NEDGE + base));
    __builtin_nontemporal_store(c1, (float4v*)(out_e + (size_t)NEDGE + base + 4));
  }
}

extern "C" void kernel_launch(void* const* d_in, const int* in_sizes, int n_in,
                              void* d_out, int out_size, void* d_ws, size_t ws_size,
                              hipStream_t stream) {
  const float* x  = (const float*)d_in[0];
  const int*   ei = (const int*)d_in[1];

  float* out   = (float*)d_out;
  float* out_x = out;                                            // 16777216
  float* out_e = out + (size_t)NUM_GRAPHS * KSEL * CFEAT;        // 16777216
  float* out_b = out_e + 2 * (size_t)NEDGE;                      // 262144
  float* out_p = out_b + (size_t)NUM_GRAPHS * KSEL;              // 262144

  // d_ws layout: [0,128K) u64 table
  unsigned long long* tab = (unsigned long long*)d_ws;

  select_kernel<<<NUM_GRAPHS, 512, 0, stream>>>(x, out_x, out_b, out_p, tab);
  edge_kernel<<<256, 1024, 0, stream>>>(ei, tab, out_e);
}